// Round 10
// baseline (377.023 us; speedup 1.0000x reference)
//
#include <hip/hip_runtime.h>
#include <math.h>

#define D_FEAT 64
#define D_OUT  128

// K_count: deg[dst]++
__global__ void k_count(const int* __restrict__ dst, int* __restrict__ deg, int E) {
    int e = blockIdx.x * blockDim.x + threadIdx.x;
    if (e >= E) return;
    atomicAdd(deg + dst[e], 1);
}

// Scan phase A: per-block (1024 elems) exclusive scan of deg -> rowptr, block totals -> partials
__global__ __launch_bounds__(256) void k_scan_a(const int* __restrict__ deg,
                                                int* __restrict__ rowptr,
                                                int* __restrict__ partials, int N) {
    __shared__ int wsum[4];
    const int t = threadIdx.x;
    const int base = blockIdx.x * 1024 + t * 4;
    int v0 = (base + 0 < N) ? deg[base + 0] : 0;
    int v1 = (base + 1 < N) ? deg[base + 1] : 0;
    int v2 = (base + 2 < N) ? deg[base + 2] : 0;
    int v3 = (base + 3 < N) ? deg[base + 3] : 0;
    int lsum = v0 + v1 + v2 + v3;
    // inclusive scan of thread sums across the 64-lane wave
    int x = lsum;
#pragma unroll
    for (int off = 1; off < 64; off <<= 1) {
        int y = __shfl_up(x, off);
        if ((t & 63) >= off) x += y;
    }
    const int wid = t >> 6;
    if ((t & 63) == 63) wsum[wid] = x;
    __syncthreads();
    int woff = 0;
    for (int w = 0; w < wid; ++w) woff += wsum[w];
    int run = woff + x - lsum;  // exclusive prefix for this thread
    if (base + 0 < N) rowptr[base + 0] = run; run += v0;
    if (base + 1 < N) rowptr[base + 1] = run; run += v1;
    if (base + 2 < N) rowptr[base + 2] = run; run += v2;
    if (base + 3 < N) rowptr[base + 3] = run;
    if (t == 0) partials[blockIdx.x] = wsum[0] + wsum[1] + wsum[2] + wsum[3];
}

// Scan phase B: single block, exclusive scan of <=128 block partials
__global__ __launch_bounds__(128) void k_scan_b(int* __restrict__ partials, int NB) {
    __shared__ int buf[128];
    const int t = threadIdx.x;
    const int orig = (t < NB) ? partials[t] : 0;
    buf[t] = orig;
    __syncthreads();
#pragma unroll
    for (int off = 1; off < 128; off <<= 1) {
        int v = (t >= off) ? buf[t - off] : 0;
        __syncthreads();
        buf[t] += v;
        __syncthreads();
    }
    if (t < NB) partials[t] = buf[t] - orig;  // exclusive
}

// Scan phase C: add block offsets; emit cursor = rowptr (k_fill's atomic base);
// set rowptr[N] = E
__global__ __launch_bounds__(256) void k_scan_c(int* __restrict__ rowptr,
                                                int* __restrict__ cursor,
                                                const int* __restrict__ partials,
                                                int N, int E) {
    const int t = threadIdx.x;
    const int base = blockIdx.x * 1024 + t * 4;
    const int add = partials[blockIdx.x];
#pragma unroll
    for (int i = 0; i < 4; ++i) {
        if (base + i < N) {
            int v = rowptr[base + i] + add;
            rowptr[base + i] = v;
            cursor[base + i] = v;
        }
    }
    if (blockIdx.x == 0 && t == 0) rowptr[N] = E;
}

// K_fill: XCD-partitioned scatter. Grid = 8 * CPP blocks; partition
// pid = blockIdx.x & 7 (matches the round-robin block->XCD dispatch heuristic;
// correctness does NOT depend on the mapping). Blocks of partition p together
// grid-stride the whole edge list (coalesced int4 dst loads) and scatter only
// edges with dst in p's range -> each srcs/cursor line is assembled densely
// inside ONE XCD's L2 (kills the 8-way sparse-dirty-line write amplification).
__global__ __launch_bounds__(256) void k_fill(const int* __restrict__ src,
                                              const int* __restrict__ dst,
                                              int* __restrict__ cursor,
                                              int* __restrict__ srcs,
                                              int E, int N) {
    const int pid = (int)(blockIdx.x & 7);
    const int cb  = (int)(blockIdx.x >> 3);
    const int cpp = (int)(gridDim.x >> 3);
    const int lo = (int)(((long long)pid * N) / 8);
    const int hi = (int)(((long long)(pid + 1) * N) / 8);

    const int nq = E >> 2;
    const int stride = cpp * 256;
    for (int q = cb * 256 + (int)threadIdx.x; q < nq; q += stride) {
        const int4 d4 = reinterpret_cast<const int4*>(dst)[q];
        const int e0 = q * 4;
        if (d4.x >= lo && d4.x < hi) { int pos = atomicAdd(cursor + d4.x, 1); srcs[pos] = src[e0 + 0]; }
        if (d4.y >= lo && d4.y < hi) { int pos = atomicAdd(cursor + d4.y, 1); srcs[pos] = src[e0 + 1]; }
        if (d4.z >= lo && d4.z < hi) { int pos = atomicAdd(cursor + d4.z, 1); srcs[pos] = src[e0 + 2]; }
        if (d4.w >= lo && d4.w < hi) { int pos = atomicAdd(cursor + d4.w, 1); srcs[pos] = src[e0 + 3]; }
    }
    // tail edges (E % 4): handled once per partition by cb==0, filtered by range
    if (cb == 0 && (int)threadIdx.x < (E & 3)) {
        int e = nq * 4 + (int)threadIdx.x;
        int d = dst[e];
        if (d >= lo && d < hi) { int pos = atomicAdd(cursor + d, 1); srcs[pos] = src[e]; }
    }
}

// K_agg: one wave per node. 4 subgroups x 16 lanes; subgroup g handles edges
// beg+g, beg+g+4, ...; lane q owns feature chunk [4q, 4q+4).
// NO running max: scores are N(0,8) (max over 1.2M edges ~ 41), exp() stays
// far inside f32 range; max-subtraction cancels exactly in Sum(ex*hk)/Sum(ex).
// dsc clamped to [-80, 80] as overflow/underflow insurance (never binds on
// this data; guarantees s > 0 for deg > 0). Pure associative reduction +
// 1-stage software pipeline.
__global__ __launch_bounds__(256) void k_agg(const float* __restrict__ hk,
                                             const float* __restrict__ hu,
                                             const int* __restrict__ rowptr,
                                             const int* __restrict__ srcs,
                                             float* __restrict__ rst, int N) {
    const int tid = blockIdx.x * blockDim.x + threadIdx.x;
    const int n = tid >> 6;          // node = one full wave
    if (n >= N) return;
    const int lane = tid & 63;
    const int q = lane & 15;         // feature chunk
    const int g = lane >> 4;         // edge subgroup

    const int beg = rowptr[n];
    const int end = rowptr[n + 1];

    const float4 hv = *reinterpret_cast<const float4*>(hu + (size_t)n * D_FEAT + q * 4);

    float s = 0.f;
    float4 acc = make_float4(0.f, 0.f, 0.f, 0.f);

    auto process = [&](const float4& a) {
        float dsc = a.x * hv.x + a.y * hv.y + a.z * hv.z + a.w * hv.w;
        dsc += __shfl_xor(dsc, 1);
        dsc += __shfl_xor(dsc, 2);
        dsc += __shfl_xor(dsc, 4);
        dsc += __shfl_xor(dsc, 8);
        const float pe = __expf(fmaxf(fminf(dsc, 80.f), -80.f));
        s += pe;
        acc.x += pe * a.x;
        acc.y += pe * a.y;
        acc.z += pe * a.z;
        acc.w += pe * a.w;
    };

    int p = beg + g;
    if (p < end) {
        float4 a = *reinterpret_cast<const float4*>(hk + (size_t)srcs[p] * D_FEAT + q * 4);
        for (p += 4; p < end; p += 4) {
            // issue next gather before the current butterfly/exp chain
            const float4 a2 = *reinterpret_cast<const float4*>(hk + (size_t)srcs[p] * D_FEAT + q * 4);
            process(a);
            a = a2;
        }
        process(a);
    }

    // merge the 4 subgroup partial sums (butterfly over lanes 16, 32)
#pragma unroll
    for (int off = 16; off <= 32; off <<= 1) {
        s     += __shfl_xor(s, off);
        acc.x += __shfl_xor(acc.x, off);
        acc.y += __shfl_xor(acc.y, off);
        acc.z += __shfl_xor(acc.z, off);
        acc.w += __shfl_xor(acc.w, off);
    }

    if (g == 0) {
        float4 o;
        if (end > beg) {
            const float inv = 1.f / s;
            o = make_float4(acc.x * inv, acc.y * inv, acc.z * inv, acc.w * inv);
        } else {
            o = make_float4(0.f, 0.f, 0.f, 0.f);  // empty segment -> rst row = 0
        }
        *reinterpret_cast<float4*>(rst + (size_t)n * D_FEAT + q * 4) = o;
    }
}

// K_fc: out = relu(rst @ W^T + b).
// 256 threads = 4 waves; wave w owns output quarter o0 = w*32; ALL four waves
// share the same 64 nodes (n = n0 + lane) -> each rst row is fetched from
// HBM/L2 once per block and hit in L1 by the other 3 waves (R9 profile showed
// FETCH = 2x rst because the 4 one-wave quarter-blocks each re-fetched it).
// Per-wave compute + LDS-transpose + coalesced store phase are byte-identical
// to the R6-proven pattern (wave-uniform W/b -> SGPR loads; 64x33 LDS chunk,
// stride 33 -> 2-way bank = free; stores cover full 64B lines).
__global__ __launch_bounds__(256) void k_fc(const float* __restrict__ rst,
                                            const float* __restrict__ W,
                                            const float* __restrict__ b,
                                            float* __restrict__ out, int N) {
    __shared__ float lds[4][64 * 33];
    const int lane = (int)(threadIdx.x & 63);
    const int w    = (int)(threadIdx.x >> 6);   // wave index = output quarter
    const int n0 = (int)blockIdx.x * 64;
    const int o0 = w * 32;
    const int n = n0 + lane;

    float4 r[16];
    if (n < N) {
        const float4* rp = reinterpret_cast<const float4*>(rst + (size_t)n * D_FEAT);
#pragma unroll
        for (int i = 0; i < 16; ++i) r[i] = rp[i];
    } else {
#pragma unroll
        for (int i = 0; i < 16; ++i) r[i] = make_float4(0.f, 0.f, 0.f, 0.f);
    }

#pragma unroll
    for (int g = 0; g < 8; ++g) {
        const int o = o0 + g * 4;
        // W rows are wave-uniform (o uniform across the wave) -> scalar loads
        const float* w0 = W + (size_t)o * D_FEAT;
        const float* w1 = w0 + D_FEAT;
        const float* w2 = w0 + 2 * D_FEAT;
        const float* w3 = w0 + 3 * D_FEAT;
        float a0 = b[o + 0];
        float a1 = b[o + 1];
        float a2 = b[o + 2];
        float a3 = b[o + 3];
#pragma unroll
        for (int k4 = 0; k4 < 16; ++k4) {
            const float4 rv = r[k4];
            const int k = k4 * 4;
            a0 += rv.x * w0[k] + rv.y * w0[k + 1] + rv.z * w0[k + 2] + rv.w * w0[k + 3];
            a1 += rv.x * w1[k] + rv.y * w1[k + 1] + rv.z * w1[k + 2] + rv.w * w1[k + 3];
            a2 += rv.x * w2[k] + rv.y * w2[k + 1] + rv.z * w2[k + 2] + rv.w * w2[k + 3];
            a3 += rv.x * w3[k] + rv.y * w3[k + 1] + rv.z * w3[k + 2] + rv.w * w3[k + 3];
        }
        lds[w][lane * 33 + g * 4 + 0] = fmaxf(a0, 0.f);
        lds[w][lane * 33 + g * 4 + 1] = fmaxf(a1, 0.f);
        lds[w][lane * 33 + g * 4 + 2] = fmaxf(a2, 0.f);
        lds[w][lane * 33 + g * 4 + 3] = fmaxf(a3, 0.f);
    }
    __syncthreads();

    // coalesced store: iteration j covers rows j*8..j*8+7 of this wave's
    // quarter, each row 128B, 8 lanes per row -> full 64B lines
    const int rrow = lane >> 3;
    const int c = (lane & 7) * 4;
#pragma unroll
    for (int j = 0; j < 8; ++j) {
        const int rr = j * 8 + rrow;
        const int nn = n0 + rr;
        if (nn < N) {
            const float* lp = lds[w] + rr * 33 + c;
            float4 v = make_float4(lp[0], lp[1], lp[2], lp[3]);
            *reinterpret_cast<float4*>(out + (size_t)nn * D_OUT + o0 + c) = v;
        }
    }
}

extern "C" void kernel_launch(void* const* d_in, const int* in_sizes, int n_in,
                              void* d_out, int out_size, void* d_ws, size_t ws_size,
                              hipStream_t stream) {
    const float* hk = (const float*)d_in[0];
    const float* hu = (const float*)d_in[1];
    const float* W  = (const float*)d_in[2];
    const float* b  = (const float*)d_in[3];
    const int* src  = (const int*)d_in[4];
    const int* dst  = (const int*)d_in[5];

    const int N = in_sizes[0] / D_FEAT;   // 100000
    const int E = in_sizes[4];            // 1200000

    // workspace layout (32-bit words, 16-word aligned sections):
    auto pad16 = [](size_t x) { return (x + 15) & ~(size_t)15; };
    size_t o_rowptr = 0;                          // N+1 ints
    size_t o_deg    = pad16(o_rowptr + N + 1);    // N ints   (zeroed)
    size_t o_cursor = o_deg + pad16(N);           // N ints   (seeded by k_scan_c)
    size_t o_srcs   = o_cursor + pad16(N);        // E ints
    size_t o_part   = o_srcs + pad16(E);          // 128 ints
    size_t o_rst    = o_part + 128;               // N*64 floats

    int* rowptr   = (int*)d_ws + o_rowptr;
    int* deg      = (int*)d_ws + o_deg;
    int* cursor   = (int*)d_ws + o_cursor;
    int* srcs     = (int*)d_ws + o_srcs;
    int* partials = (int*)d_ws + o_part;
    float* rst    = (float*)d_ws + o_rst;

    // zero deg only (cursor is fully written by k_scan_c)
    hipMemsetAsync(deg, 0, pad16(N) * sizeof(int), stream);

    const int B = 256;
    const int g_edge = (E + B - 1) / B;
    const int NB = (N + 1023) / 1024;   // 98 for N=100000 (must be <= 128)

    k_count<<<g_edge, B, 0, stream>>>(dst, deg, E);
    k_scan_a<<<NB, 256, 0, stream>>>(deg, rowptr, partials, N);
    k_scan_b<<<1, 128, 0, stream>>>(partials, NB);
    k_scan_c<<<NB, 256, 0, stream>>>(rowptr, cursor, partials, N, E);
    // 8 partitions x 256 blocks = 2048 blocks (fills the chip's block capacity)
    k_fill<<<2048, 256, 0, stream>>>(src, dst, cursor, srcs, E, N);
    k_agg<<<(N + 3) / 4, 256, 0, stream>>>(hk, hu, rowptr, srcs, rst, N);
    // 4 waves/block, each wave = one output quarter over the same 64 nodes
    k_fc<<<(N + 63) / 64, 256, 0, stream>>>(rst, W, b, (float*)d_out, N);
}

// Round 11
// 290.076 us; speedup vs baseline: 1.2997x; 1.2997x over previous
//
#include <hip/hip_runtime.h>
#include <math.h>

#define D_FEAT 64
#define D_OUT  128

typedef __attribute__((ext_vector_type(8))) short bf16x8;
typedef __attribute__((ext_vector_type(4))) float f32x4;

// f32 -> bf16 round-to-nearest-even (no NaN handling needed for this data)
__device__ __forceinline__ unsigned short f2bf(float f) {
    unsigned u = __float_as_uint(f);
    unsigned r = (u + 0x7FFFu + ((u >> 16) & 1u)) >> 16;
    return (unsigned short)r;
}

// K_count: deg[dst]++
__global__ void k_count(const int* __restrict__ dst, int* __restrict__ deg, int E) {
    int e = blockIdx.x * blockDim.x + threadIdx.x;
    if (e >= E) return;
    atomicAdd(deg + dst[e], 1);
}

// Scan phase A: per-block (1024 elems) exclusive scan of deg -> rowptr, block totals -> partials
__global__ __launch_bounds__(256) void k_scan_a(const int* __restrict__ deg,
                                                int* __restrict__ rowptr,
                                                int* __restrict__ partials, int N) {
    __shared__ int wsum[4];
    const int t = threadIdx.x;
    const int base = blockIdx.x * 1024 + t * 4;
    int v0 = (base + 0 < N) ? deg[base + 0] : 0;
    int v1 = (base + 1 < N) ? deg[base + 1] : 0;
    int v2 = (base + 2 < N) ? deg[base + 2] : 0;
    int v3 = (base + 3 < N) ? deg[base + 3] : 0;
    int lsum = v0 + v1 + v2 + v3;
    int x = lsum;
#pragma unroll
    for (int off = 1; off < 64; off <<= 1) {
        int y = __shfl_up(x, off);
        if ((t & 63) >= off) x += y;
    }
    const int wid = t >> 6;
    if ((t & 63) == 63) wsum[wid] = x;
    __syncthreads();
    int woff = 0;
    for (int w = 0; w < wid; ++w) woff += wsum[w];
    int run = woff + x - lsum;  // exclusive prefix for this thread
    if (base + 0 < N) rowptr[base + 0] = run; run += v0;
    if (base + 1 < N) rowptr[base + 1] = run; run += v1;
    if (base + 2 < N) rowptr[base + 2] = run; run += v2;
    if (base + 3 < N) rowptr[base + 3] = run;
    if (t == 0) partials[blockIdx.x] = wsum[0] + wsum[1] + wsum[2] + wsum[3];
}

// Scan phase B: single block, exclusive scan of <=128 block partials
__global__ __launch_bounds__(128) void k_scan_b(int* __restrict__ partials, int NB) {
    __shared__ int buf[128];
    const int t = threadIdx.x;
    const int orig = (t < NB) ? partials[t] : 0;
    buf[t] = orig;
    __syncthreads();
#pragma unroll
    for (int off = 1; off < 128; off <<= 1) {
        int v = (t >= off) ? buf[t - off] : 0;
        __syncthreads();
        buf[t] += v;
        __syncthreads();
    }
    if (t < NB) partials[t] = buf[t] - orig;  // exclusive
}

// Scan phase C: add block offsets; emit cursor = rowptr; set rowptr[N] = E
__global__ __launch_bounds__(256) void k_scan_c(int* __restrict__ rowptr,
                                                int* __restrict__ cursor,
                                                const int* __restrict__ partials,
                                                int N, int E) {
    const int t = threadIdx.x;
    const int base = blockIdx.x * 1024 + t * 4;
    const int add = partials[blockIdx.x];
#pragma unroll
    for (int i = 0; i < 4; ++i) {
        if (base + i < N) {
            int v = rowptr[base + i] + add;
            rowptr[base + i] = v;
            cursor[base + i] = v;
        }
    }
    if (blockIdx.x == 0 && t == 0) rowptr[N] = E;
}

// K_fill: XCD-partitioned scatter (R8-proven: kills 8-way sparse-dirty-line
// write amplification on srcs/cursor).
__global__ __launch_bounds__(256) void k_fill(const int* __restrict__ src,
                                              const int* __restrict__ dst,
                                              int* __restrict__ cursor,
                                              int* __restrict__ srcs,
                                              int E, int N) {
    const int pid = (int)(blockIdx.x & 7);
    const int cb  = (int)(blockIdx.x >> 3);
    const int cpp = (int)(gridDim.x >> 3);
    const int lo = (int)(((long long)pid * N) / 8);
    const int hi = (int)(((long long)(pid + 1) * N) / 8);

    const int nq = E >> 2;
    const int stride = cpp * 256;
    for (int q = cb * 256 + (int)threadIdx.x; q < nq; q += stride) {
        const int4 d4 = reinterpret_cast<const int4*>(dst)[q];
        const int e0 = q * 4;
        if (d4.x >= lo && d4.x < hi) { int pos = atomicAdd(cursor + d4.x, 1); srcs[pos] = src[e0 + 0]; }
        if (d4.y >= lo && d4.y < hi) { int pos = atomicAdd(cursor + d4.y, 1); srcs[pos] = src[e0 + 1]; }
        if (d4.z >= lo && d4.z < hi) { int pos = atomicAdd(cursor + d4.z, 1); srcs[pos] = src[e0 + 2]; }
        if (d4.w >= lo && d4.w < hi) { int pos = atomicAdd(cursor + d4.w, 1); srcs[pos] = src[e0 + 3]; }
    }
    if (cb == 0 && (int)threadIdx.x < (E & 3)) {
        int e = nq * 4 + (int)threadIdx.x;
        int d = dst[e];
        if (d >= lo && d < hi) { int pos = atomicAdd(cursor + d, 1); srcs[pos] = src[e]; }
    }
}

// K_agg: one wave per node; no-running-max softmax (R9-proven; scores N(0,8),
// clamp [-80,80] as insurance); 1-stage pipelined gather. Output rst in BF16
// (RNE) -- halves the write and feeds k_fc's MFMA directly.
__global__ __launch_bounds__(256) void k_agg(const float* __restrict__ hk,
                                             const float* __restrict__ hu,
                                             const int* __restrict__ rowptr,
                                             const int* __restrict__ srcs,
                                             unsigned short* __restrict__ rst_bf, int N) {
    const int tid = blockIdx.x * blockDim.x + threadIdx.x;
    const int n = tid >> 6;          // node = one full wave
    if (n >= N) return;
    const int lane = tid & 63;
    const int q = lane & 15;         // feature chunk
    const int g = lane >> 4;         // edge subgroup

    const int beg = rowptr[n];
    const int end = rowptr[n + 1];

    const float4 hv = *reinterpret_cast<const float4*>(hu + (size_t)n * D_FEAT + q * 4);

    float s = 0.f;
    float4 acc = make_float4(0.f, 0.f, 0.f, 0.f);

    auto process = [&](const float4& a) {
        float dsc = a.x * hv.x + a.y * hv.y + a.z * hv.z + a.w * hv.w;
        dsc += __shfl_xor(dsc, 1);
        dsc += __shfl_xor(dsc, 2);
        dsc += __shfl_xor(dsc, 4);
        dsc += __shfl_xor(dsc, 8);
        const float pe = __expf(fmaxf(fminf(dsc, 80.f), -80.f));
        s += pe;
        acc.x += pe * a.x;
        acc.y += pe * a.y;
        acc.z += pe * a.z;
        acc.w += pe * a.w;
    };

    int p = beg + g;
    if (p < end) {
        float4 a = *reinterpret_cast<const float4*>(hk + (size_t)srcs[p] * D_FEAT + q * 4);
        for (p += 4; p < end; p += 4) {
            const float4 a2 = *reinterpret_cast<const float4*>(hk + (size_t)srcs[p] * D_FEAT + q * 4);
            process(a);
            a = a2;
        }
        process(a);
    }

#pragma unroll
    for (int off = 16; off <= 32; off <<= 1) {
        s     += __shfl_xor(s, off);
        acc.x += __shfl_xor(acc.x, off);
        acc.y += __shfl_xor(acc.y, off);
        acc.z += __shfl_xor(acc.z, off);
        acc.w += __shfl_xor(acc.w, off);
    }

    if (g == 0) {
        ushort4 o;
        if (end > beg) {
            const float inv = 1.f / s;
            o.x = f2bf(acc.x * inv);
            o.y = f2bf(acc.y * inv);
            o.z = f2bf(acc.z * inv);
            o.w = f2bf(acc.w * inv);
        } else {
            o.x = o.y = o.z = o.w = 0;  // empty segment -> rst row = 0
        }
        *reinterpret_cast<ushort4*>(rst_bf + (size_t)n * D_FEAT + q * 4) = o;
    }
}

// K_wcvt: W (128x64 f32) -> bf16 copy, once per launch. 8192 elems.
__global__ __launch_bounds__(256) void k_wcvt(const float* __restrict__ W,
                                              unsigned short* __restrict__ Wbf) {
    const int i = (blockIdx.x * 256 + threadIdx.x) * 4;
    const float4 w = *reinterpret_cast<const float4*>(W + i);
    ushort4 o;
    o.x = f2bf(w.x); o.y = f2bf(w.y); o.z = f2bf(w.z); o.w = f2bf(w.w);
    *reinterpret_cast<ushort4*>(Wbf + i) = o;
}

// K_fc (MFMA): out = relu(rst @ W^T + bias), rst/W in bf16, f32 accumulate.
// Block = 256 threads = 4 waves; wave wv owns nodes [n0+wv*16, +16) x all 128
// outputs = 8 tiles x (K=64 -> 2 mfma_f32_16x16x32_bf16).
// Fragment mapping (m89/m91-verified):
//   A: row = lane&15, k = 8*(lane>>4)+i   -> lane loads 8 contiguous bf16 of
//      its rst row (16B)
//   B: col = lane&15, k = 8*(lane>>4)+i   -> B[k][c] = W[c][k]: 8 contiguous
//      bf16 of W row (16B), from the 16KB L2-resident Wbf
//   D: col = lane&15, row = 4*(lane>>4)+r
// Epilogue: +bias, relu; per (tile,reg) each 16-lane group stores 16
// consecutive floats = one full 64B line.
__global__ __launch_bounds__(256) void k_fc(const unsigned short* __restrict__ rst_bf,
                                            const unsigned short* __restrict__ Wbf,
                                            const float* __restrict__ bias,
                                            float* __restrict__ out, int N) {
    const int l   = (int)(threadIdx.x & 63);
    const int wv  = (int)(threadIdx.x >> 6);
    const int c16 = l & 15;          // A-row / B-col / D-col within tile
    const int kg  = l >> 4;          // k-group (0..3)
    const int n0  = (int)blockIdx.x * 64 + wv * 16;

    // B fragments: 8 tiles x 2 k-halves (preloaded; 64 VGPRs)
    bf16x8 bf[8][2];
#pragma unroll
    for (int t = 0; t < 8; ++t) {
#pragma unroll
        for (int kh = 0; kh < 2; ++kh) {
            bf[t][kh] = *reinterpret_cast<const bf16x8*>(
                Wbf + (size_t)(t * 16 + c16) * D_FEAT + kh * 32 + kg * 8);
        }
    }

    // A fragments: this lane's rst row (n0 + c16), 2 k-halves
    const int na = n0 + c16;
    bf16x8 af[2];
    if (na < N) {
#pragma unroll
        for (int kh = 0; kh < 2; ++kh) {
            af[kh] = *reinterpret_cast<const bf16x8*>(
                rst_bf + (size_t)na * D_FEAT + kh * 32 + kg * 8);
        }
    } else {
        af[0] = (bf16x8)0;
        af[1] = (bf16x8)0;
    }

    f32x4 acc[8];
#pragma unroll
    for (int t = 0; t < 8; ++t) {
        f32x4 z = {0.f, 0.f, 0.f, 0.f};
        z = __builtin_amdgcn_mfma_f32_16x16x32_bf16(af[0], bf[t][0], z, 0, 0, 0);
        acc[t] = __builtin_amdgcn_mfma_f32_16x16x32_bf16(af[1], bf[t][1], z, 0, 0, 0);
    }

    // epilogue: D row = 4*kg + r, col = c16
#pragma unroll
    for (int t = 0; t < 8; ++t) {
        const float bv = bias[t * 16 + c16];
#pragma unroll
        for (int r = 0; r < 4; ++r) {
            const int nn = n0 + kg * 4 + r;
            if (nn < N)
                out[(size_t)nn * D_OUT + t * 16 + c16] = fmaxf(acc[t][r] + bv, 0.f);
        }
    }
}

extern "C" void kernel_launch(void* const* d_in, const int* in_sizes, int n_in,
                              void* d_out, int out_size, void* d_ws, size_t ws_size,
                              hipStream_t stream) {
    const float* hk = (const float*)d_in[0];
    const float* hu = (const float*)d_in[1];
    const float* W  = (const float*)d_in[2];
    const float* b  = (const float*)d_in[3];
    const int* src  = (const int*)d_in[4];
    const int* dst  = (const int*)d_in[5];

    const int N = in_sizes[0] / D_FEAT;   // 100000
    const int E = in_sizes[4];            // 1200000

    // workspace layout (32-bit words, 16-word aligned sections):
    auto pad16 = [](size_t x) { return (x + 15) & ~(size_t)15; };
    size_t o_rowptr = 0;                          // N+1 ints
    size_t o_deg    = pad16(o_rowptr + N + 1);    // N ints   (zeroed)
    size_t o_cursor = o_deg + pad16(N);           // N ints   (seeded by k_scan_c)
    size_t o_srcs   = o_cursor + pad16(N);        // E ints
    size_t o_part   = o_srcs + pad16(E);          // 128 ints
    size_t o_rstbf  = pad16(o_part + 128);        // N*64 bf16 = N*32 words
    size_t o_wbf    = o_rstbf + pad16((size_t)N * 32);  // 8192 bf16 = 4096 words

    int* rowptr   = (int*)d_ws + o_rowptr;
    int* deg      = (int*)d_ws + o_deg;
    int* cursor   = (int*)d_ws + o_cursor;
    int* srcs     = (int*)d_ws + o_srcs;
    int* partials = (int*)d_ws + o_part;
    unsigned short* rst_bf = (unsigned short*)((int*)d_ws + o_rstbf);
    unsigned short* Wbf    = (unsigned short*)((int*)d_ws + o_wbf);

    // zero deg only (cursor is fully written by k_scan_c)
    hipMemsetAsync(deg, 0, pad16(N) * sizeof(int), stream);

    const int B = 256;
    const int g_edge = (E + B - 1) / B;
    const int NB = (N + 1023) / 1024;   // 98 for N=100000 (must be <= 128)

    k_wcvt<<<(D_OUT * D_FEAT) / (256 * 4), 256, 0, stream>>>(W, Wbf);
    k_count<<<g_edge, B, 0, stream>>>(dst, deg, E);
    k_scan_a<<<NB, 256, 0, stream>>>(deg, rowptr, partials, N);
    k_scan_b<<<1, 128, 0, stream>>>(partials, NB);
    k_scan_c<<<NB, 256, 0, stream>>>(rowptr, cursor, partials, N, E);
    // 8 partitions x 256 blocks = 2048 blocks
    k_fill<<<2048, 256, 0, stream>>>(src, dst, cursor, srcs, E, N);
    k_agg<<<(N + 3) / 4, 256, 0, stream>>>(hk, hu, rowptr, srcs, rst_bf, N);
    // MFMA FC: 4 waves/block, 64 nodes/block
    k_fc<<<(N + 63) / 64, 256, 0, stream>>>(rst_bf, Wbf, b, (float*)d_out, N);
}